// Round 8
// baseline (1141.100 us; speedup 1.0000x reference)
//
#include <hip/hip_runtime.h>
#include <math.h>

typedef float f2 __attribute__((ext_vector_type(2)));
typedef float f2u __attribute__((ext_vector_type(2), aligned(4)));
typedef float f4 __attribute__((ext_vector_type(4)));

#define BN 8
#define CIN 3
#define HH 512
#define WW 512
#define KK 9
#define PATCH 27
#define TAPBLK 96  // 56 (wy,wx) pair floats | 28 wm | 12 contraction = 96 = 6x dwordx16

// ws layout, tap k block of 96 floats (base 64B-aligned):
//  r in [0,56):  pair q=r>>1, half=r&1 -> w_off[(2k+half)*27+q], q>=27 -> 0
//  r in [56,84): i=r-56 -> w_off[(18+k)*27+i], i>=27 -> 0
//  r in [84,96): j=r-84, c=j>>2, o=j&3 -> o<3 ? w_def[o*27 + c*9 + k] : 0
__global__ void reorder_weights(const float* __restrict__ w_off,
                                const float* __restrict__ w_def,
                                float* __restrict__ ws)
{
    for (int idx = threadIdx.x; idx < KK * TAPBLK; idx += blockDim.x) {
        const int k = idx / TAPBLK;
        const int r = idx % TAPBLK;
        float v = 0.0f;
        if (r < 56) {
            const int q = r >> 1, half = r & 1;
            if (q < PATCH) v = w_off[(2 * k + half) * PATCH + q];
        } else if (r < 84) {
            const int i = r - 56;
            if (i < PATCH) v = w_off[(18 + k) * PATCH + i];
        } else {
            const int j = r - 84;
            const int c = j >> 2, o = j & 3;
            if (o < 3) v = w_def[o * PATCH + c * KK + k];
        }
        ws[idx] = v;
    }
}

// __launch_bounds__(256, 8): 8 waves/EU -> VGPR cap 64. This is the whole
// round-8 change vs round 7: keep the fully-unrolled pipelined schedule
// (measured 2.4x per-wave issue efficiency) but stay on the 8-waves/SIMD
// side of the 64-VGPR occupancy granule (waves halve at 64/128/256).
__global__ __launch_bounds__(256, 8) void deform_fused_kernel(
    const float* __restrict__ x,
    const float* __restrict__ wsw,    // reordered weights, 864 floats (uniform -> SMEM)
    const float* __restrict__ b_off,
    const float* __restrict__ b_def,
    float* __restrict__ out)
{
    const int w = blockIdx.x * blockDim.x + threadIdx.x;
    const int h = blockIdx.y;
    const int b = blockIdx.z;

    const size_t plane = (size_t)HH * WW;
    const float* xb = x + (size_t)b * CIN * plane;

    // ---- 3x3x3 zero-padded patch, flat index = c*9 + t; pad elem 27 = 0 ----
    float patch[28];
    patch[27] = 0.0f;
    #pragma unroll
    for (int c = 0; c < CIN; ++c) {
        const float* xp = xb + c * plane;
        #pragma unroll
        for (int t = 0; t < KK; ++t) {
            const int yy = h + t / 3 - 1;
            const int xx = w + t % 3 - 1;
            const bool in = (yy >= 0) & (yy < HH) & (xx >= 0) & (xx < WW);
            patch[c * KK + t] = in ? xp[yy * WW + xx] : 0.0f;
        }
    }

    const float hf = (float)h;
    const float wf = (float)w;

    f2 acc01 = { b_def[0], b_def[1] };
    float acc2 = b_def[2];

    // ---- prologue: conv for tap 0 (proven per-tap structure) ----
    f2 oyx;
    float om;
    {
        const float* blk = wsw;   // tap 0
        f2 a = { b_off[0], b_off[1] };
        float s = b_off[18];
        #pragma unroll
        for (int j = 0; j < 14; ++j) {
            const f4 wq = *(const f4*)(blk + 4 * j);
            const float p0 = patch[2 * j];
            const float p1 = patch[2 * j + 1];
            const f2 w0 = { wq.x, wq.y };
            const f2 w1 = { wq.z, wq.w };
            const f2 pp0 = { p0, p0 };
            const f2 pp1 = { p1, p1 };
            a = __builtin_elementwise_fma(w0, pp0, a);
            a = __builtin_elementwise_fma(w1, pp1, a);
        }
        #pragma unroll
        for (int j = 0; j < 7; ++j) {
            const f4 wm4 = *(const f4*)(blk + 56 + 4 * j);
            s = fmaf(wm4.x, patch[4 * j],     s);
            s = fmaf(wm4.y, patch[4 * j + 1], s);
            s = fmaf(wm4.z, patch[4 * j + 2], s);
            s = fmaf(wm4.w, patch[4 * j + 3], s);
        }
        oyx = a;
        om = s;
    }

    // ---- software-pipelined tap loop, fully unrolled (scheduler hoists tap
    //      k+1's weight s_loads under tap k's conv), VGPRs capped at 64 ----
    // iteration k: (A) issue gathers for tap k-1  (B) conv tap k  (C) consume tap k-1
    #pragma unroll
    for (int k = 1; k <= KK; ++k) {
        const int kp = k - 1;
        const float* blkp = wsw + kp * TAPBLK;

        // -- phase A: contraction weights (uniform, early) + sampling for tap kp --
        const f4 cw0 = *(const f4*)(blkp + 84);
        const f4 cw1 = *(const f4*)(blkp + 88);
        const f4 cw2 = *(const f4*)(blkp + 92);

        const float m = 1.0f / (1.0f + __expf(-om));

        const float py = hf + (float)(kp / 3 - 1) + oyx.x;
        const float px = wf + (float)(kp % 3 - 1) + oyx.y;
        const float y0f = floorf(py);
        const float x0f = floorf(px);
        const float dy = py - y0f;
        const float dx = px - x0f;
        const int y0 = (int)y0f;
        const int x0 = (int)x0f;

        const f2 dxp = { 1.0f - dx, dx };
        const f2 wT = dxp * (1.0f - dy);   // (w00, w01)
        const f2 wB = dxp * dy;            // (w10, w11)

        const int interior = (y0 >= 0) & (y0 + 1 < HH) & (x0 >= 0) & (x0 + 1 < WW);

        f2 vT0, vB0, vT1, vB1, vT2, vB2;   // gathered 2x2 corners per channel
        if (__all(interior)) {
            const int idx = y0 * WW + x0;
            const float* xp0 = xb + idx;
            const float* xp1 = xp0 + plane;
            const float* xp2 = xp1 + plane;
            vT0 = *(const f2u*)(xp0);  vB0 = *(const f2u*)(xp0 + WW);
            vT1 = *(const f2u*)(xp1);  vB1 = *(const f2u*)(xp1 + WW);
            vT2 = *(const f2u*)(xp2);  vB2 = *(const f2u*)(xp2 + WW);
        } else {
            const bool vy0 = (y0 >= 0)     & (y0 < HH);
            const bool vy1 = (y0 + 1 >= 0) & (y0 + 1 < HH);
            const bool vx0 = (x0 >= 0)     & (x0 < WW);
            const bool vx1 = (x0 + 1 >= 0) & (x0 + 1 < WW);

            const int yc0 = min(max(y0, 0), HH - 1);
            const int yc1 = min(max(y0 + 1, 0), HH - 1);
            const int xc0 = min(max(x0, 0), WW - 1);
            const int xc1 = min(max(x0 + 1, 0), WW - 1);

            const float* xp0 = xb;
            const float* xp1 = xp0 + plane;
            const float* xp2 = xp1 + plane;

            vT0.x = (vy0 & vx0) ? xp0[yc0 * WW + xc0] : 0.0f;
            vT0.y = (vy0 & vx1) ? xp0[yc0 * WW + xc1] : 0.0f;
            vB0.x = (vy1 & vx0) ? xp0[yc1 * WW + xc0] : 0.0f;
            vB0.y = (vy1 & vx1) ? xp0[yc1 * WW + xc1] : 0.0f;
            vT1.x = (vy0 & vx0) ? xp1[yc0 * WW + xc0] : 0.0f;
            vT1.y = (vy0 & vx1) ? xp1[yc0 * WW + xc1] : 0.0f;
            vB1.x = (vy1 & vx0) ? xp1[yc1 * WW + xc0] : 0.0f;
            vB1.y = (vy1 & vx1) ? xp1[yc1 * WW + xc1] : 0.0f;
            vT2.x = (vy0 & vx0) ? xp2[yc0 * WW + xc0] : 0.0f;
            vT2.y = (vy0 & vx1) ? xp2[yc0 * WW + xc1] : 0.0f;
            vB2.x = (vy1 & vx0) ? xp2[yc1 * WW + xc0] : 0.0f;
            vB2.y = (vy1 & vx1) ? xp2[yc1 * WW + xc1] : 0.0f;
        }

        // -- phase B: conv for tap k (independent of in-flight gathers) --
        if (k < KK) {
            const float* blk = wsw + k * TAPBLK;
            f2 a = { b_off[2 * k], b_off[2 * k + 1] };
            float s = b_off[18 + k];
            #pragma unroll
            for (int j = 0; j < 14; ++j) {
                const f4 wq = *(const f4*)(blk + 4 * j);
                const float p0 = patch[2 * j];
                const float p1 = patch[2 * j + 1];
                const f2 w0 = { wq.x, wq.y };
                const f2 w1 = { wq.z, wq.w };
                const f2 pp0 = { p0, p0 };
                const f2 pp1 = { p1, p1 };
                a = __builtin_elementwise_fma(w0, pp0, a);
                a = __builtin_elementwise_fma(w1, pp1, a);
            }
            #pragma unroll
            for (int j = 0; j < 7; ++j) {
                const f4 wm4 = *(const f4*)(blk + 56 + 4 * j);
                s = fmaf(wm4.x, patch[4 * j],     s);
                s = fmaf(wm4.y, patch[4 * j + 1], s);
                s = fmaf(wm4.z, patch[4 * j + 2], s);
                s = fmaf(wm4.w, patch[4 * j + 3], s);
            }
            oyx = a;
            om = s;
        }

        // -- phase C: consume tap kp's gathers (vmcnt wait lands here) --
        {
            f2 s0 = vT0 * wT;
            s0 = __builtin_elementwise_fma(vB0, wB, s0);
            const float val0 = (s0.x + s0.y) * m;
            f2 s1 = vT1 * wT;
            s1 = __builtin_elementwise_fma(vB1, wB, s1);
            const float val1 = (s1.x + s1.y) * m;
            f2 s2 = vT2 * wT;
            s2 = __builtin_elementwise_fma(vB2, wB, s2);
            const float val2 = (s2.x + s2.y) * m;

            const f2 w01_0 = { cw0.x, cw0.y };
            const f2 w01_1 = { cw1.x, cw1.y };
            const f2 w01_2 = { cw2.x, cw2.y };
            const f2 vv0 = { val0, val0 };
            const f2 vv1 = { val1, val1 };
            const f2 vv2 = { val2, val2 };
            acc01 = __builtin_elementwise_fma(w01_0, vv0, acc01);
            acc2 = fmaf(cw0.z, val0, acc2);
            acc01 = __builtin_elementwise_fma(w01_1, vv1, acc01);
            acc2 = fmaf(cw1.z, val1, acc2);
            acc01 = __builtin_elementwise_fma(w01_2, vv2, acc01);
            acc2 = fmaf(cw2.z, val2, acc2);
        }
    }

    const size_t base = (size_t)b * (CIN * plane) + (size_t)h * WW + w;
    out[base]             = acc01.x;
    out[base + plane]     = acc01.y;
    out[base + 2 * plane] = acc2;
}

extern "C" void kernel_launch(void* const* d_in, const int* in_sizes, int n_in,
                              void* d_out, int out_size, void* d_ws, size_t ws_size,
                              hipStream_t stream) {
    const float* x     = (const float*)d_in[0];
    const float* w_off = (const float*)d_in[1];
    const float* b_off = (const float*)d_in[2];
    const float* w_def = (const float*)d_in[3];
    const float* b_def = (const float*)d_in[4];
    float* out = (float*)d_out;
    float* wsw = (float*)d_ws;   // 864 floats of reordered weights

    reorder_weights<<<1, 256, 0, stream>>>(w_off, w_def, wsw);

    dim3 block(256, 1, 1);
    dim3 grid(WW / 256, HH, BN);  // (2, 512, 8)
    deform_fused_kernel<<<grid, block, 0, stream>>>(x, wsw, b_off, b_def, out);
}

// Round 9
// 182.020 us; speedup vs baseline: 6.2691x; 6.2691x over previous
//
#include <hip/hip_runtime.h>
#include <math.h>

typedef float f2 __attribute__((ext_vector_type(2)));
typedef float f2u __attribute__((ext_vector_type(2), aligned(4)));

#define BN 8
#define CIN 3
#define HH 512
#define WW 512
#define KK 9
#define PATCH 27
#define TAPBLK 96  // 56 (wy,wx) pair floats | 28 wm | 12 contraction = 96 = 6x dwordx16

// ws layout, tap k block of 96 floats (base 64B-aligned) — identical to r5:
//  r in [0,56):  pair q=r>>1, half=r&1 -> w_off[(2k+half)*27+q], q>=27 -> 0
//  r in [56,84): i=r-56 -> w_off[(18+k)*27+i], i>=27 -> 0
//  r in [84,96): j=r-84, c=j>>2, o=j&3 -> o<3 ? w_def[o*27 + c*9 + k] : 0
__global__ void reorder_weights(const float* __restrict__ w_off,
                                const float* __restrict__ w_def,
                                float* __restrict__ ws)
{
    for (int idx = threadIdx.x; idx < KK * TAPBLK; idx += blockDim.x) {
        const int k = idx / TAPBLK;
        const int r = idx % TAPBLK;
        float v = 0.0f;
        if (r < 56) {
            const int q = r >> 1, half = r & 1;
            if (q < PATCH) v = w_off[(2 * k + half) * PATCH + q];
        } else if (r < 84) {
            const int i = r - 56;
            if (i < PATCH) v = w_off[(18 + k) * PATCH + i];
        } else {
            const int j = r - 84;
            const int c = j >> 2, o = j & 3;
            if (o < 3) v = w_def[o * PATCH + c * KK + k];
        }
        ws[idx] = v;
    }
}

__global__ __launch_bounds__(256) void deform_fused_kernel(
    const float* __restrict__ x,
    const float* __restrict__ wsw,    // reordered weights, 864 floats (uniform -> SMEM)
    const float* __restrict__ b_off,
    const float* __restrict__ b_def,
    float* __restrict__ out)
{
    const int w = blockIdx.x * blockDim.x + threadIdx.x;
    const int h = blockIdx.y;
    const int b = blockIdx.z;

    const size_t plane = (size_t)HH * WW;
    const float* xb = x + (size_t)b * CIN * plane;

    // ---- 3x3x3 zero-padded patch, flat index = c*9 + t; pad elem 27 = 0 ----
    float patch[28];
    patch[27] = 0.0f;
    #pragma unroll
    for (int c = 0; c < CIN; ++c) {
        const float* xp = xb + c * plane;
        #pragma unroll
        for (int t = 0; t < KK; ++t) {
            const int yy = h + t / 3 - 1;
            const int xx = w + t % 3 - 1;
            const bool in = (yy >= 0) & (yy < HH) & (xx >= 0) & (xx < WW);
            patch[c * KK + t] = in ? xp[yy * WW + xx] : 0.0f;
        }
    }

    const float hf = (float)h;
    const float wf = (float)w;

    // scalar accumulators (no packed ops anywhere in the arithmetic)
    float acc0 = b_def[0];
    float acc1 = b_def[1];
    float acc2 = b_def[2];

    // ---- prologue: conv for tap 0, all-scalar fmaf (weights straight from SGPR) ----
    float oy, ox, om;
    {
        const float* blk = wsw;   // tap 0
        float a0 = b_off[0], a1 = b_off[1], s = b_off[18];
        #pragma unroll
        for (int q = 0; q < 28; ++q) {
            a0 = fmaf(blk[2 * q],     patch[q], a0);
            a1 = fmaf(blk[2 * q + 1], patch[q], a1);
        }
        #pragma unroll
        for (int i = 0; i < 28; ++i) {
            s = fmaf(blk[56 + i], patch[i], s);
        }
        oy = a0; ox = a1; om = s;
    }

    // ---- software-pipelined tap loop (r5 schedule, scalar arithmetic) ----
    // iteration k: (A) issue gathers for tap k-1  (B) conv tap k  (C) consume tap k-1
    #pragma unroll 1
    for (int k = 1; k <= KK; ++k) {
        const int kp = k - 1;
        const float* blkp = wsw + kp * TAPBLK;

        // -- phase A: contraction weights (uniform scalars) + sampling for tap kp --
        const float cw00 = blkp[84], cw01 = blkp[85], cw02 = blkp[86];
        const float cw10 = blkp[88], cw11 = blkp[89], cw12 = blkp[90];
        const float cw20 = blkp[92], cw21 = blkp[93], cw22 = blkp[94];

        const float m = 1.0f / (1.0f + __expf(-om));

        const float py = hf + (float)(kp / 3 - 1) + oy;
        const float px = wf + (float)(kp % 3 - 1) + ox;
        const float y0f = floorf(py);
        const float x0f = floorf(px);
        const float dy = py - y0f;
        const float dx = px - x0f;
        const int y0 = (int)y0f;
        const int x0 = (int)x0f;

        // scalar bilinear weights
        const float omdy = 1.0f - dy;
        const float omdx = 1.0f - dx;
        const float w00 = omdx * omdy;
        const float w01 = dx * omdy;
        const float w10 = omdx * dy;
        const float w11 = dx * dy;

        const int interior = (y0 >= 0) & (y0 + 1 < HH) & (x0 >= 0) & (x0 + 1 < WW);

        f2 vT0, vB0, vT1, vB1, vT2, vB2;   // gathered 2x2 corners per channel
        if (__all(interior)) {
            const int idx = y0 * WW + x0;
            const float* xp0 = xb + idx;
            const float* xp1 = xp0 + plane;
            const float* xp2 = xp1 + plane;
            vT0 = *(const f2u*)(xp0);  vB0 = *(const f2u*)(xp0 + WW);
            vT1 = *(const f2u*)(xp1);  vB1 = *(const f2u*)(xp1 + WW);
            vT2 = *(const f2u*)(xp2);  vB2 = *(const f2u*)(xp2 + WW);
        } else {
            const bool vy0 = (y0 >= 0)     & (y0 < HH);
            const bool vy1 = (y0 + 1 >= 0) & (y0 + 1 < HH);
            const bool vx0 = (x0 >= 0)     & (x0 < WW);
            const bool vx1 = (x0 + 1 >= 0) & (x0 + 1 < WW);

            const int yc0 = min(max(y0, 0), HH - 1);
            const int yc1 = min(max(y0 + 1, 0), HH - 1);
            const int xc0 = min(max(x0, 0), WW - 1);
            const int xc1 = min(max(x0 + 1, 0), WW - 1);

            const float* xp0 = xb;
            const float* xp1 = xp0 + plane;
            const float* xp2 = xp1 + plane;

            vT0.x = (vy0 & vx0) ? xp0[yc0 * WW + xc0] : 0.0f;
            vT0.y = (vy0 & vx1) ? xp0[yc0 * WW + xc1] : 0.0f;
            vB0.x = (vy1 & vx0) ? xp0[yc1 * WW + xc0] : 0.0f;
            vB0.y = (vy1 & vx1) ? xp0[yc1 * WW + xc1] : 0.0f;
            vT1.x = (vy0 & vx0) ? xp1[yc0 * WW + xc0] : 0.0f;
            vT1.y = (vy0 & vx1) ? xp1[yc0 * WW + xc1] : 0.0f;
            vB1.x = (vy1 & vx0) ? xp1[yc1 * WW + xc0] : 0.0f;
            vB1.y = (vy1 & vx1) ? xp1[yc1 * WW + xc1] : 0.0f;
            vT2.x = (vy0 & vx0) ? xp2[yc0 * WW + xc0] : 0.0f;
            vT2.y = (vy0 & vx1) ? xp2[yc0 * WW + xc1] : 0.0f;
            vB2.x = (vy1 & vx0) ? xp2[yc1 * WW + xc0] : 0.0f;
            vB2.y = (vy1 & vx1) ? xp2[yc1 * WW + xc1] : 0.0f;
        }

        // -- phase B: conv for tap k, all-scalar (independent of in-flight gathers) --
        if (k < KK) {
            const float* blk = wsw + k * TAPBLK;
            float a0 = b_off[2 * k], a1 = b_off[2 * k + 1], s = b_off[18 + k];
            #pragma unroll
            for (int q = 0; q < 28; ++q) {
                a0 = fmaf(blk[2 * q],     patch[q], a0);
                a1 = fmaf(blk[2 * q + 1], patch[q], a1);
            }
            #pragma unroll
            for (int i = 0; i < 28; ++i) {
                s = fmaf(blk[56 + i], patch[i], s);
            }
            oy = a0; ox = a1; om = s;
        }

        // -- phase C: consume tap kp's gathers, all-scalar --
        {
            float v0 = vT0.x * w00;
            v0 = fmaf(vT0.y, w01, v0);
            v0 = fmaf(vB0.x, w10, v0);
            v0 = fmaf(vB0.y, w11, v0);
            const float val0 = v0 * m;

            float v1 = vT1.x * w00;
            v1 = fmaf(vT1.y, w01, v1);
            v1 = fmaf(vB1.x, w10, v1);
            v1 = fmaf(vB1.y, w11, v1);
            const float val1 = v1 * m;

            float v2 = vT2.x * w00;
            v2 = fmaf(vT2.y, w01, v2);
            v2 = fmaf(vB2.x, w10, v2);
            v2 = fmaf(vB2.y, w11, v2);
            const float val2 = v2 * m;

            acc0 = fmaf(cw00, val0, acc0);
            acc1 = fmaf(cw01, val0, acc1);
            acc2 = fmaf(cw02, val0, acc2);
            acc0 = fmaf(cw10, val1, acc0);
            acc1 = fmaf(cw11, val1, acc1);
            acc2 = fmaf(cw12, val1, acc2);
            acc0 = fmaf(cw20, val2, acc0);
            acc1 = fmaf(cw21, val2, acc1);
            acc2 = fmaf(cw22, val2, acc2);
        }
    }

    const size_t base = (size_t)b * (CIN * plane) + (size_t)h * WW + w;
    out[base]             = acc0;
    out[base + plane]     = acc1;
    out[base + 2 * plane] = acc2;
}

extern "C" void kernel_launch(void* const* d_in, const int* in_sizes, int n_in,
                              void* d_out, int out_size, void* d_ws, size_t ws_size,
                              hipStream_t stream) {
    const float* x     = (const float*)d_in[0];
    const float* w_off = (const float*)d_in[1];
    const float* b_off = (const float*)d_in[2];
    const float* w_def = (const float*)d_in[3];
    const float* b_def = (const float*)d_in[4];
    float* out = (float*)d_out;
    float* wsw = (float*)d_ws;   // 864 floats of reordered weights

    reorder_weights<<<1, 256, 0, stream>>>(w_off, w_def, wsw);

    dim3 block(256, 1, 1);
    dim3 grid(WW / 256, HH, BN);  // (2, 512, 8)
    deform_fused_kernel<<<grid, block, 0, stream>>>(x, wsw, b_off, b_def, out);
}